// Round 2
// baseline (913.334 us; speedup 1.0000x reference)
//
#include <hip/hip_runtime.h>
#include <hip/hip_bf16.h>

#define B_ 16
#define S_ 512
#define E_ 512
#define H_ 8
#define D_ 64
#define TQ 16

// ---------------------------------------------------------------------------
// Kernel A: quantum projections.  One wave per (proj, b, s, h) group.
// theta_q = dot(x[b,s,h,:], Win[q,:]) + bin[q] + w[q];  c_q = cos(theta_q)
// VQC closed form (RX compose; CNOT ring = XOR of independent bits):
//   Z0=c1c2c3, Z1=c0c1, Z2=c0c1c2, Z3=c0c1c2c3
// out[d] = sum_q Z_q*Wout[d][q] + bout[d].  Q/K/V stored fp32 in (B,H,S,D).
// ---------------------------------------------------------------------------
__global__ __launch_bounds__(256) void proj_kernel(
    const float* __restrict__ q_in, const float* __restrict__ k_in, const float* __restrict__ v_in,
    const float* __restrict__ Wq_in, const float* __restrict__ bq_in,
    const float* __restrict__ Wk_in, const float* __restrict__ bk_in,
    const float* __restrict__ Wv_in, const float* __restrict__ bv_in,
    const float* __restrict__ wvq, const float* __restrict__ wvk, const float* __restrict__ wvv,
    const float* __restrict__ Wq, const float* __restrict__ bq,
    const float* __restrict__ Wk, const float* __restrict__ bk,
    const float* __restrict__ Wv, const float* __restrict__ bv,
    float* __restrict__ Qw, float* __restrict__ Kw, float* __restrict__ Vw)
{
    const int wave = threadIdx.x >> 6;
    const int lane = threadIdx.x & 63;
    const int g = blockIdx.x * 4 + wave;          // 3*65536 groups
    const int p = g >> 16;                        // projection 0/1/2
    const int m = g & 0xFFFF;                     // b*4096 + s*8 + h
    const int h = m & 7;
    const int s = (m >> 3) & 511;
    const int b = m >> 12;

    const float *X, *Win, *bin, *wv, *Wout, *bout;
    float* dst;
    if (p == 0)      { X = q_in; Win = Wq_in; bin = bq_in; wv = wvq; Wout = Wq; bout = bq; dst = Qw; }
    else if (p == 1) { X = k_in; Win = Wk_in; bin = bk_in; wv = wvk; Wout = Wk; bout = bk; dst = Kw; }
    else             { X = v_in; Win = Wv_in; bin = bv_in; wv = wvv; Wout = Wv; bout = bv; dst = Vw; }

    const float x = X[((size_t)(b * S_ + s)) * E_ + h * 64 + lane];
    float p0 = x * Win[0 * 64 + lane];
    float p1 = x * Win[1 * 64 + lane];
    float p2 = x * Win[2 * 64 + lane];
    float p3 = x * Win[3 * 64 + lane];
#pragma unroll
    for (int off = 32; off >= 1; off >>= 1) {
        p0 += __shfl_xor(p0, off, 64);
        p1 += __shfl_xor(p1, off, 64);
        p2 += __shfl_xor(p2, off, 64);
        p3 += __shfl_xor(p3, off, 64);
    }
    const float t0 = p0 + bin[0] + wv[0];
    const float t1 = p1 + bin[1] + wv[1];
    const float t2 = p2 + bin[2] + wv[2];
    const float t3 = p3 + bin[3] + wv[3];
    const float c0 = cosf(t0), c1 = cosf(t1), c2 = cosf(t2), c3 = cosf(t3);
    const float z0 = c1 * c2 * c3;
    const float z1 = c0 * c1;
    const float z2 = z1 * c2;
    const float z3 = z2 * c3;

    const float out = z0 * Wout[lane * 4 + 0] + z1 * Wout[lane * 4 + 1] +
                      z2 * Wout[lane * 4 + 2] + z3 * Wout[lane * 4 + 3] +
                      bout[lane];
    dst[(((size_t)(b * H_ + h)) * S_ + s) * D_ + lane] = out;
}

// ---------------------------------------------------------------------------
// Kernel B: attention.  One block = 16 q rows of one (b,h).
// energy = Q K^T;  attn = softmax(energy/32);  O = attn V   (O in (B,S,E))
// ---------------------------------------------------------------------------
__global__ __launch_bounds__(256) void attn_kernel(
    const float* __restrict__ Qw, const float* __restrict__ Kw, const float* __restrict__ Vw,
    float* __restrict__ Ow)
{
    __shared__ float Qs[TQ][64];        // 4 KB
    __shared__ float Sc[TQ][512];       // 32 KB
    __shared__ float KVs[64][65];       // 16.25 KB (padded)
    __shared__ float inv_s[TQ];

    const int t = threadIdx.x;
    const int lane = t & 63;
    const int w = t >> 6;
    const int bh = blockIdx.x >> 5;     // 32 q-tiles per (b,h)
    const int qt = blockIdx.x & 31;
    const int q0 = qt * TQ;
    const int b = bh >> 3, h = bh & 7;

    const float* Qp = Qw + (size_t)bh * S_ * D_;
    const float* Kp = Kw + (size_t)bh * S_ * D_;
    const float* Vp = Vw + (size_t)bh * S_ * D_;

    // load Q tile (16x64)
    for (int i = t; i < TQ * 64; i += 256) {
        const int ql = i >> 6, d = i & 63;
        Qs[ql][d] = Qp[(size_t)(q0 + ql) * 64 + d];
    }
    __syncthreads();

    // ---- phase 1: scores.  Each wave covers rows {w, w+4, w+8, w+12}; lane = k within chunk.
    for (int ch = 0; ch < 8; ch++) {
        for (int i = t; i < 4096; i += 256) {
            const int r = i >> 6, d = i & 63;
            KVs[r][d] = Kp[(size_t)(ch * 64 + r) * 64 + d];
        }
        __syncthreads();
        float a0 = 0.f, a1 = 0.f, a2 = 0.f, a3 = 0.f;
#pragma unroll
        for (int d = 0; d < 64; d++) {
            const float kv = KVs[lane][d];
            a0 += kv * Qs[w][d];
            a1 += kv * Qs[w + 4][d];
            a2 += kv * Qs[w + 8][d];
            a3 += kv * Qs[w + 12][d];
        }
        Sc[w][ch * 64 + lane]      = a0;
        Sc[w + 4][ch * 64 + lane]  = a1;
        Sc[w + 8][ch * 64 + lane]  = a2;
        Sc[w + 12][ch * 64 + lane] = a3;
        __syncthreads();
    }

    // ---- phase 2: softmax (scale = 1/(D/2) = 1/32, max-subtracted)
    for (int rr = 0; rr < 4; rr++) {
        const int ql = w + rr * 4;
        float mx = -1e30f;
#pragma unroll
        for (int j = 0; j < 8; j++) mx = fmaxf(mx, Sc[ql][j * 64 + lane]);
#pragma unroll
        for (int off = 32; off >= 1; off >>= 1) mx = fmaxf(mx, __shfl_xor(mx, off, 64));
        float sum = 0.f;
#pragma unroll
        for (int j = 0; j < 8; j++) {
            const float e = __expf((Sc[ql][j * 64 + lane] - mx) * 0.03125f);
            Sc[ql][j * 64 + lane] = e;
            sum += e;
        }
#pragma unroll
        for (int off = 32; off >= 1; off >>= 1) sum += __shfl_xor(sum, off, 64);
        if (lane == 0) inv_s[ql] = 1.0f / sum;
    }
    __syncthreads();

    // ---- phase 3: O = P V.  lane = d; each wave accumulates its 4 rows.
    float o0 = 0.f, o1 = 0.f, o2 = 0.f, o3 = 0.f;
    for (int ch = 0; ch < 8; ch++) {
        for (int i = t; i < 4096; i += 256) {
            const int r = i >> 6, d = i & 63;
            KVs[r][d] = Vp[(size_t)(ch * 64 + r) * 64 + d];
        }
        __syncthreads();
#pragma unroll
        for (int k = 0; k < 64; k++) {
            const float vv = KVs[k][lane];
            o0 += Sc[w][ch * 64 + k] * vv;
            o1 += Sc[w + 4][ch * 64 + k] * vv;
            o2 += Sc[w + 8][ch * 64 + k] * vv;
            o3 += Sc[w + 12][ch * 64 + k] * vv;
        }
        __syncthreads();
    }
    const size_t obase = ((size_t)b * S_) * E_ + (size_t)h * 64 + lane;
    Ow[obase + (size_t)(q0 + w) * E_]        = o0 * inv_s[w];
    Ow[obase + (size_t)(q0 + w + 4) * E_]    = o1 * inv_s[w + 4];
    Ow[obase + (size_t)(q0 + w + 8) * E_]    = o2 * inv_s[w + 8];
    Ow[obase + (size_t)(q0 + w + 12) * E_]   = o3 * inv_s[w + 12];
}

// ---------------------------------------------------------------------------
// Kernel C: out = [Qflat | O] @ Wo^T + bo.   (8192 x 1024) @ (1024 x 512)
// 64x64 output tile per block, 4x4 register micro-tile per thread.
// ---------------------------------------------------------------------------
__global__ __launch_bounds__(256) void out_kernel(
    const float* __restrict__ Qw, const float* __restrict__ Ow,
    const float* __restrict__ Wo, const float* __restrict__ bo,
    float* __restrict__ out)
{
    __shared__ float As[64][65];
    __shared__ float Bs[64][65];

    const int t = threadIdx.x;
    const int et = blockIdx.x & 7;      // 8 e-tiles
    const int nt = blockIdx.x >> 3;     // 128 n-tiles
    const int n0 = nt * 64, e0 = et * 64;
    const int tn = t >> 4, te = t & 15;

    float acc[4][4] = {};

    for (int j0 = 0; j0 < 1024; j0 += 64) {
        // A tile: cat[n0..n0+63][j0..j0+63]
        if (j0 < 512) {
            const int hh = j0 >> 6;
#pragma unroll
            for (int i = 0; i < 16; i++) {
                const int ii = i * 256 + t;
                const int nl = ii >> 6, jl = ii & 63;
                const int n = n0 + nl;
                const int bb = n >> 9, s = n & 511;
                As[nl][jl] = Qw[(((size_t)(bb * 8 + hh)) * 512 + s) * 64 + jl];
            }
        } else {
#pragma unroll
            for (int i = 0; i < 16; i++) {
                const int ii = i * 256 + t;
                const int nl = ii >> 6, jl = ii & 63;
                As[nl][jl] = Ow[(size_t)(n0 + nl) * 512 + (j0 - 512) + jl];
            }
        }
        // B tile (transposed): Bs[j][e] = Wo[e0+e][j0+j]
#pragma unroll
        for (int i = 0; i < 16; i++) {
            const int ii = i * 256 + t;
            const int el = ii >> 6, jl = ii & 63;
            Bs[jl][el] = Wo[(size_t)(e0 + el) * 1024 + j0 + jl];
        }
        __syncthreads();

#pragma unroll 8
        for (int kk = 0; kk < 64; kk++) {
            const float a0 = As[tn * 4 + 0][kk];
            const float a1 = As[tn * 4 + 1][kk];
            const float a2 = As[tn * 4 + 2][kk];
            const float a3 = As[tn * 4 + 3][kk];
            const float b0 = Bs[kk][te * 4 + 0];
            const float b1 = Bs[kk][te * 4 + 1];
            const float b2 = Bs[kk][te * 4 + 2];
            const float b3 = Bs[kk][te * 4 + 3];
            acc[0][0] += a0 * b0; acc[0][1] += a0 * b1; acc[0][2] += a0 * b2; acc[0][3] += a0 * b3;
            acc[1][0] += a1 * b0; acc[1][1] += a1 * b1; acc[1][2] += a1 * b2; acc[1][3] += a1 * b3;
            acc[2][0] += a2 * b0; acc[2][1] += a2 * b1; acc[2][2] += a2 * b2; acc[2][3] += a2 * b3;
            acc[3][0] += a3 * b0; acc[3][1] += a3 * b1; acc[3][2] += a3 * b2; acc[3][3] += a3 * b3;
        }
        __syncthreads();
    }

#pragma unroll
    for (int i = 0; i < 4; i++) {
        const int n = n0 + tn * 4 + i;
#pragma unroll
        for (int j = 0; j < 4; j++) {
            const int e = e0 + te * 4 + j;
            out[(size_t)n * 512 + e] = acc[i][j] + bo[e];
        }
    }
}

// ---------------------------------------------------------------------------
extern "C" void kernel_launch(void* const* d_in, const int* in_sizes, int n_in,
                              void* d_out, int out_size, void* d_ws, size_t ws_size,
                              hipStream_t stream)
{
    const float* q_in  = (const float*)d_in[0];
    const float* k_in  = (const float*)d_in[1];
    const float* v_in  = (const float*)d_in[2];
    // d_in[3] = mask (int32) — semantic no-op in the reference
    const float* Wq_in = (const float*)d_in[4];
    const float* bq_in = (const float*)d_in[5];
    const float* Wk_in = (const float*)d_in[6];
    const float* bk_in = (const float*)d_in[7];
    const float* Wv_in = (const float*)d_in[8];
    const float* bv_in = (const float*)d_in[9];
    const float* wvq   = (const float*)d_in[10];
    const float* wvk   = (const float*)d_in[11];
    const float* wvv   = (const float*)d_in[12];
    const float* Wq    = (const float*)d_in[13];
    const float* bq    = (const float*)d_in[14];
    const float* Wk    = (const float*)d_in[15];
    const float* bk    = (const float*)d_in[16];
    const float* Wv    = (const float*)d_in[17];
    const float* bv    = (const float*)d_in[18];
    const float* Wo    = (const float*)d_in[19];
    const float* bo    = (const float*)d_in[20];

    float* ws = (float*)d_ws;
    float* Qw = ws;                          // (B,H,S,D) 4M floats
    float* Kw = ws + (size_t)(1 << 22);      // (B,H,S,D)
    float* Vw = ws + (size_t)(2 << 22);      // (B,H,S,D)
    float* Ow = ws + (size_t)3 * (1 << 22);  // (B,S,E)

    proj_kernel<<<49152, 256, 0, stream>>>(q_in, k_in, v_in,
        Wq_in, bq_in, Wk_in, bk_in, Wv_in, bv_in,
        wvq, wvk, wvv, Wq, bq, Wk, bk, Wv, bv,
        Qw, Kw, Vw);
    attn_kernel<<<4096, 256, 0, stream>>>(Qw, Kw, Vw, Ow);
    out_kernel<<<1024, 256, 0, stream>>>(Qw, Ow, Wo, bo, (float*)d_out);
}

// Round 3
// 282.733 us; speedup vs baseline: 3.2304x; 3.2304x over previous
//
#include <hip/hip_runtime.h>
#include <hip/hip_bf16.h>

#define B_ 16
#define S_ 512
#define E_ 512
#define H_ 8
#define D_ 64

typedef __hip_bfloat16 bf16;
typedef unsigned short u16;
typedef __attribute__((ext_vector_type(8))) short short8;
typedef __attribute__((ext_vector_type(4))) float floatx4;

__device__ __forceinline__ u16 f2b(float x) {
    bf16 h = __float2bfloat16(x);
    return *reinterpret_cast<u16*>(&h);
}
__device__ __forceinline__ short8 ld8(const u16* p) { return *(const short8*)p; }

// ---------------------------------------------------------------------------
// Kernel A: quantum projections (closed-form VQC).  One wave per (proj,b,s,h).
//   Z0=c1c2c3, Z1=c0c1, Z2=c0c1c2, Z3=c0c1c2c3 with c_q=cos(x·Win_q+bin_q+w_q)
// Writes Q/K/V as bf16 in (B,H,S,D).
// ---------------------------------------------------------------------------
__global__ __launch_bounds__(256) void proj_kernel(
    const float* __restrict__ q_in, const float* __restrict__ k_in, const float* __restrict__ v_in,
    const float* __restrict__ Wq_in, const float* __restrict__ bq_in,
    const float* __restrict__ Wk_in, const float* __restrict__ bk_in,
    const float* __restrict__ Wv_in, const float* __restrict__ bv_in,
    const float* __restrict__ wvq, const float* __restrict__ wvk, const float* __restrict__ wvv,
    const float* __restrict__ Wq, const float* __restrict__ bq,
    const float* __restrict__ Wk, const float* __restrict__ bk,
    const float* __restrict__ Wv, const float* __restrict__ bv,
    u16* __restrict__ Qb, u16* __restrict__ Kb, u16* __restrict__ Vb)
{
    const int wave = threadIdx.x >> 6;
    const int lane = threadIdx.x & 63;
    const int g = blockIdx.x * 4 + wave;          // 3*65536 groups
    const int p = g >> 16;
    const int m = g & 0xFFFF;                     // b*4096 + s*8 + h
    const int h = m & 7;
    const int s = (m >> 3) & 511;
    const int b = m >> 12;

    const float *X, *Win, *bin, *wv, *Wout, *bout;
    u16* dst;
    if (p == 0)      { X = q_in; Win = Wq_in; bin = bq_in; wv = wvq; Wout = Wq; bout = bq; dst = Qb; }
    else if (p == 1) { X = k_in; Win = Wk_in; bin = bk_in; wv = wvk; Wout = Wk; bout = bk; dst = Kb; }
    else             { X = v_in; Win = Wv_in; bin = bv_in; wv = wvv; Wout = Wv; bout = bv; dst = Vb; }

    const float x = X[((size_t)(b * S_ + s)) * E_ + h * 64 + lane];
    float p0 = x * Win[0 * 64 + lane];
    float p1 = x * Win[1 * 64 + lane];
    float p2 = x * Win[2 * 64 + lane];
    float p3 = x * Win[3 * 64 + lane];
#pragma unroll
    for (int off = 32; off >= 1; off >>= 1) {
        p0 += __shfl_xor(p0, off, 64);
        p1 += __shfl_xor(p1, off, 64);
        p2 += __shfl_xor(p2, off, 64);
        p3 += __shfl_xor(p3, off, 64);
    }
    const float c0 = cosf(p0 + bin[0] + wv[0]);
    const float c1 = cosf(p1 + bin[1] + wv[1]);
    const float c2 = cosf(p2 + bin[2] + wv[2]);
    const float c3 = cosf(p3 + bin[3] + wv[3]);
    const float z0 = c1 * c2 * c3;
    const float z1 = c0 * c1;
    const float z2 = z1 * c2;
    const float z3 = z2 * c3;

    const float out = z0 * Wout[lane * 4 + 0] + z1 * Wout[lane * 4 + 1] +
                      z2 * Wout[lane * 4 + 2] + z3 * Wout[lane * 4 + 3] +
                      bout[lane];
    dst[(((size_t)(b * H_ + h)) * S_ + s) * D_ + lane] = f2b(out);
}

// ---------------------------------------------------------------------------
// Kernel B: flash-style MFMA attention.  Block = 64 q-rows of one (b,h),
// 4 waves x 16 rows.  8 chunks of 64 k-positions.  softmax(energy/32) online.
// O written bf16 to (B,S,E).
// ---------------------------------------------------------------------------
__global__ __launch_bounds__(256) void attn_kernel(
    const u16* __restrict__ Qb, const u16* __restrict__ Kb, const u16* __restrict__ Vb,
    u16* __restrict__ Ob)
{
    __shared__ __align__(16) u16 Qs[64][72];        // [qrow][d]
    __shared__ __align__(16) u16 Ks[64][72];        // [kpos][d]   ([N][K] for QK^T)
    __shared__ __align__(16) u16 Vt[64][72];        // [d][kpos]   ([N][K] for PV)
    __shared__ __align__(16) u16 Ps[4][16][72];     // per-wave P  [qrow][kpos]

    const int t = threadIdx.x, lane = t & 63, w = t >> 6;
    const int bh = blockIdx.x >> 3;
    const int q0 = (blockIdx.x & 7) * 64;
    const int b = bh >> 3, h = bh & 7;

    const u16* Qp = Qb + (size_t)bh * (S_ * D_) + (size_t)q0 * D_;
    const u16* Kp = Kb + (size_t)bh * (S_ * D_);
    const u16* Vp = Vb + (size_t)bh * (S_ * D_);

    // stage Q tile (64x64)
    for (int i = t; i < 512; i += 256) {
        const int r = i & 63, c = (i >> 6) * 8;
        *(short8*)&Qs[r][c] = ld8(&Qp[r * 64 + c]);
    }
    __syncthreads();

    const int nl = lane & 15;           // n-index within 16x16 tile
    const int kg = (lane >> 4) * 8;     // k-group offset
    short8 qa0, qa1;
    {
        const int mr = w * 16 + nl;
        qa0 = ld8(&Qs[mr][kg]);
        qa1 = ld8(&Qs[mr][kg + 32]);
    }

    floatx4 of[4];
    float m_run[4], l_run[4];
#pragma unroll
    for (int r = 0; r < 4; ++r) { m_run[r] = -1e30f; l_run[r] = 0.f; }
#pragma unroll
    for (int nt = 0; nt < 4; ++nt) of[nt] = 0.f;

    for (int ch = 0; ch < 8; ++ch) {
        __syncthreads();
        // stage K chunk [kpos][d]
        for (int i = t; i < 512; i += 256) {
            const int r = i & 63, c = (i >> 6) * 8;
            *(short8*)&Ks[r][c] = ld8(&Kp[(ch * 64 + r) * 64 + c]);
        }
        // stage V chunk transposed [d][kpos] (column writes: 2-way bank, free)
        for (int i = t; i < 512; i += 256) {
            const int r = i & 63, c = (i >> 6) * 8;
            short8 v = ld8(&Vp[(ch * 64 + r) * 64 + c]);
#pragma unroll
            for (int j = 0; j < 8; ++j) Vt[c + j][r] = (u16)((short*)&v)[j];
        }
        __syncthreads();

        // S = Q K^T  (fp32 accum)
        floatx4 sf[4];
#pragma unroll
        for (int nt = 0; nt < 4; ++nt) sf[nt] = 0.f;
#pragma unroll
        for (int nt = 0; nt < 4; ++nt) {
            sf[nt] = __builtin_amdgcn_mfma_f32_16x16x32_bf16(qa0, ld8(&Ks[nt * 16 + nl][kg]), sf[nt], 0, 0, 0);
            sf[nt] = __builtin_amdgcn_mfma_f32_16x16x32_bf16(qa1, ld8(&Ks[nt * 16 + nl][kg + 32]), sf[nt], 0, 0, 0);
        }

        // online softmax on t = S/32.  Row r held by 16 lanes (same lane>>4).
        float mnew[4], alpha[4], rs[4];
#pragma unroll
        for (int r = 0; r < 4; ++r) {
            float mx = fmaxf(fmaxf(sf[0][r], sf[1][r]), fmaxf(sf[2][r], sf[3][r])) * 0.03125f;
#pragma unroll
            for (int off = 1; off < 16; off <<= 1) mx = fmaxf(mx, __shfl_xor(mx, off, 64));
            mnew[r] = fmaxf(m_run[r], mx);
            alpha[r] = __expf(m_run[r] - mnew[r]);
            rs[r] = 0.f;
        }
        const int prow = (lane >> 4) * 4;
#pragma unroll
        for (int nt = 0; nt < 4; ++nt) {
#pragma unroll
            for (int r = 0; r < 4; ++r) {
                const float pv = __expf(sf[nt][r] * 0.03125f - mnew[r]);
                rs[r] += pv;
                Ps[w][prow + r][nt * 16 + nl] = f2b(pv);
                of[nt][r] *= alpha[r];
            }
        }
#pragma unroll
        for (int r = 0; r < 4; ++r) {
            float sum = rs[r];
#pragma unroll
            for (int off = 1; off < 16; off <<= 1) sum += __shfl_xor(sum, off, 64);
            l_run[r] = l_run[r] * alpha[r] + sum;
            m_run[r] = mnew[r];
        }

        // O += P V   (P same-wave LDS round-trip; compiler orders ds ops)
        const short8 pa0 = ld8(&Ps[w][nl][kg]);
        const short8 pa1 = ld8(&Ps[w][nl][kg + 32]);
#pragma unroll
        for (int nt = 0; nt < 4; ++nt) {
            of[nt] = __builtin_amdgcn_mfma_f32_16x16x32_bf16(pa0, ld8(&Vt[nt * 16 + nl][kg]), of[nt], 0, 0, 0);
            of[nt] = __builtin_amdgcn_mfma_f32_16x16x32_bf16(pa1, ld8(&Vt[nt * 16 + nl][kg + 32]), of[nt], 0, 0, 0);
        }
    }

    // epilogue: O/l, store bf16 to (B,S,E)
    float inv[4];
#pragma unroll
    for (int r = 0; r < 4; ++r) inv[r] = 1.0f / l_run[r];
    const int srow = q0 + w * 16 + (lane >> 4) * 4;
#pragma unroll
    for (int r = 0; r < 4; ++r) {
        const size_t base = ((size_t)(b * S_ + srow + r)) * E_ + h * 64 + nl;
#pragma unroll
        for (int nt = 0; nt < 4; ++nt)
            Ob[base + nt * 16] = f2b(of[nt][r] * inv[r]);
    }
}

// ---------------------------------------------------------------------------
// Kernel C: out = [Qflat | O] @ Wo^T + bo  via bf16 MFMA, fp32 accum.
// (8192 x 1024) x (1024 x 512).  128x128 tile/block, 2x2 waves, 4x4 frags.
// ---------------------------------------------------------------------------
__global__ __launch_bounds__(256) void out_kernel(
    const u16* __restrict__ Qb, const u16* __restrict__ Ob,
    const float* __restrict__ Wo, const float* __restrict__ bo,
    float* __restrict__ out)
{
    __shared__ __align__(16) u16 As[128][72];   // cat rows [m][k]
    __shared__ __align__(16) u16 Bs[128][72];   // Wo rows  [n=e][k=j]

    const int t = threadIdx.x, lane = t & 63, w = t >> 6;
    const int e0 = (blockIdx.x & 3) * 128;
    const int n0 = (blockIdx.x >> 2) * 128;
    const int wr = (w >> 1) * 64, wc = (w & 1) * 64;
    const int nl = lane & 15, kg = (lane >> 4) * 8;

    floatx4 acc[4][4];
#pragma unroll
    for (int i = 0; i < 4; ++i)
#pragma unroll
        for (int j = 0; j < 4; ++j) acc[i][j] = 0.f;

    for (int j0 = 0; j0 < 1024; j0 += 64) {
        // stage A: cat[n0+r][j0+c]
        for (int i = t; i < 1024; i += 256) {
            const int r = i & 127, c = (i >> 7) * 8;
            const int n = n0 + r;
            const u16* src = (j0 < 512)
                ? &Qb[(((size_t)(n >> 9) * 8 + (j0 >> 6)) * 512 + (n & 511)) * 64 + c]
                : &Ob[(size_t)n * 512 + (j0 - 512) + c];
            *(short8*)&As[r][c] = ld8(src);
        }
        // stage B: Wo[e0+r][j0+c], fp32 -> bf16
        for (int i = t; i < 1024; i += 256) {
            const int r = i & 127, c = (i >> 7) * 8;
            const float* src = &Wo[(size_t)(e0 + r) * 1024 + j0 + c];
            u16 tmp[8] __attribute__((aligned(16)));
#pragma unroll
            for (int j = 0; j < 8; ++j) tmp[j] = f2b(src[j]);
            *(short8*)&Bs[r][c] = *(short8*)tmp;
        }
        __syncthreads();

        short8 af[4][2], bfr[4][2];
#pragma unroll
        for (int mt = 0; mt < 4; ++mt) {
            af[mt][0] = ld8(&As[wr + mt * 16 + nl][kg]);
            af[mt][1] = ld8(&As[wr + mt * 16 + nl][kg + 32]);
        }
#pragma unroll
        for (int nt = 0; nt < 4; ++nt) {
            bfr[nt][0] = ld8(&Bs[wc + nt * 16 + nl][kg]);
            bfr[nt][1] = ld8(&Bs[wc + nt * 16 + nl][kg + 32]);
        }
#pragma unroll
        for (int mt = 0; mt < 4; ++mt)
#pragma unroll
            for (int nt = 0; nt < 4; ++nt) {
                acc[mt][nt] = __builtin_amdgcn_mfma_f32_16x16x32_bf16(af[mt][0], bfr[nt][0], acc[mt][nt], 0, 0, 0);
                acc[mt][nt] = __builtin_amdgcn_mfma_f32_16x16x32_bf16(af[mt][1], bfr[nt][1], acc[mt][nt], 0, 0, 0);
            }
        __syncthreads();
    }

    const int prow = (lane >> 4) * 4;
#pragma unroll
    for (int mt = 0; mt < 4; ++mt)
#pragma unroll
        for (int r = 0; r < 4; ++r) {
            const int n = n0 + wr + mt * 16 + prow + r;
#pragma unroll
            for (int nt = 0; nt < 4; ++nt) {
                const int e = e0 + wc + nt * 16 + nl;
                out[(size_t)n * 512 + e] = acc[mt][nt][r] + bo[e];
            }
        }
}

// ---------------------------------------------------------------------------
extern "C" void kernel_launch(void* const* d_in, const int* in_sizes, int n_in,
                              void* d_out, int out_size, void* d_ws, size_t ws_size,
                              hipStream_t stream)
{
    const float* q_in  = (const float*)d_in[0];
    const float* k_in  = (const float*)d_in[1];
    const float* v_in  = (const float*)d_in[2];
    // d_in[3] = mask (int32) — semantic no-op in the reference
    const float* Wq_in = (const float*)d_in[4];
    const float* bq_in = (const float*)d_in[5];
    const float* Wk_in = (const float*)d_in[6];
    const float* bk_in = (const float*)d_in[7];
    const float* Wv_in = (const float*)d_in[8];
    const float* bv_in = (const float*)d_in[9];
    const float* wvq   = (const float*)d_in[10];
    const float* wvk   = (const float*)d_in[11];
    const float* wvv   = (const float*)d_in[12];
    const float* Wq    = (const float*)d_in[13];
    const float* bq    = (const float*)d_in[14];
    const float* Wk    = (const float*)d_in[15];
    const float* bk    = (const float*)d_in[16];
    const float* Wv    = (const float*)d_in[17];
    const float* bv    = (const float*)d_in[18];
    const float* Wo    = (const float*)d_in[19];
    const float* bo    = (const float*)d_in[20];

    u16* ws = (u16*)d_ws;
    u16* Qb = ws;                          // (B,H,S,D) bf16, 4M elems
    u16* Kb = ws + (size_t)(1 << 22);
    u16* Vb = ws + (size_t)(2 << 22);
    u16* Ob = ws + (size_t)3 * (1 << 22);  // (B,S,E) bf16

    proj_kernel<<<49152, 256, 0, stream>>>(q_in, k_in, v_in,
        Wq_in, bq_in, Wk_in, bk_in, Wv_in, bv_in,
        wvq, wvk, wvv, Wq, bq, Wk, bk, Wv, bv,
        Qb, Kb, Vb);
    attn_kernel<<<1024, 256, 0, stream>>>(Qb, Kb, Vb, Ob);
    out_kernel<<<256, 256, 0, stream>>>(Qb, Ob, Wo, bo, (float*)d_out);
}

// Round 4
// 231.323 us; speedup vs baseline: 3.9483x; 1.2222x over previous
//
#include <hip/hip_runtime.h>
#include <hip/hip_bf16.h>

#define B_ 16
#define S_ 512
#define E_ 512
#define H_ 8
#define D_ 64

typedef __hip_bfloat16 bf16;
typedef unsigned short u16;
typedef __attribute__((ext_vector_type(8))) short short8;
typedef __attribute__((ext_vector_type(4))) float floatx4;

__device__ __forceinline__ u16 f2b(float x) {
    bf16 h = __float2bfloat16(x);
    return *reinterpret_cast<u16*>(&h);
}
__device__ __forceinline__ short8 ld8(const u16* p) { return *(const short8*)p; }

// ---------------------------------------------------------------------------
// Kernel W: Wo fp32 -> bf16 (512x1024, converted once, reused by out_kernel)
// ---------------------------------------------------------------------------
__global__ __launch_bounds__(256) void wconv_kernel(
    const float* __restrict__ Wo, u16* __restrict__ Wb)
{
    const int i = (blockIdx.x * 256 + threadIdx.x) * 8;
    const float4 a = *(const float4*)&Wo[i];
    const float4 b = *(const float4*)&Wo[i + 4];
    u16 tmp[8] __attribute__((aligned(16)));
    tmp[0] = f2b(a.x); tmp[1] = f2b(a.y); tmp[2] = f2b(a.z); tmp[3] = f2b(a.w);
    tmp[4] = f2b(b.x); tmp[5] = f2b(b.y); tmp[6] = f2b(b.z); tmp[7] = f2b(b.w);
    *(short8*)&Wb[i] = *(short8*)tmp;
}

// ---------------------------------------------------------------------------
// Kernel A: quantum projections (closed-form VQC).  One wave per (proj,b,s,h).
// lane = (q = lane>>4, dsub = lane&15): 4-elem partial dot, 4-level reduce,
// ONE __cosf per lane, 3-shuffle gather of the other cosines.
//   Z0=c1c2c3, Z1=c0c1, Z2=c0c1c2, Z3=c0c1c2c3
// Q/K/V written bf16 in (B,H,S,D).
// ---------------------------------------------------------------------------
__global__ __launch_bounds__(256) void proj_kernel(
    const float* __restrict__ q_in, const float* __restrict__ k_in, const float* __restrict__ v_in,
    const float* __restrict__ Wq_in, const float* __restrict__ bq_in,
    const float* __restrict__ Wk_in, const float* __restrict__ bk_in,
    const float* __restrict__ Wv_in, const float* __restrict__ bv_in,
    const float* __restrict__ wvq, const float* __restrict__ wvk, const float* __restrict__ wvv,
    const float* __restrict__ Wq, const float* __restrict__ bq,
    const float* __restrict__ Wk, const float* __restrict__ bk,
    const float* __restrict__ Wv, const float* __restrict__ bv,
    u16* __restrict__ Qb, u16* __restrict__ Kb, u16* __restrict__ Vb)
{
    const int wave = threadIdx.x >> 6;
    const int lane = threadIdx.x & 63;
    const int g = blockIdx.x * 4 + wave;          // 3*65536 groups
    const int p = g >> 16;
    const int m = g & 0xFFFF;                     // b*4096 + s*8 + h
    const int h = m & 7;
    const int s = (m >> 3) & 511;
    const int b = m >> 12;

    const float *X, *Win, *bin, *wv, *Wout, *bout;
    u16* dst;
    if (p == 0)      { X = q_in; Win = Wq_in; bin = bq_in; wv = wvq; Wout = Wq; bout = bq; dst = Qb; }
    else if (p == 1) { X = k_in; Win = Wk_in; bin = bk_in; wv = wvk; Wout = Wk; bout = bk; dst = Kb; }
    else             { X = v_in; Win = Wv_in; bin = bv_in; wv = wvv; Wout = Wv; bout = bv; dst = Vb; }

    const int q = lane >> 4;
    const int dsub = lane & 15;
    const float* xp = X + ((size_t)(b * S_ + s)) * E_ + h * 64;
    const float* wp = Win + q * 64;

    float part = 0.f;
#pragma unroll
    for (int j = 0; j < 4; ++j)
        part += xp[dsub + 16 * j] * wp[dsub + 16 * j];
#pragma unroll
    for (int off = 8; off >= 1; off >>= 1)
        part += __shfl_xor(part, off, 64);

    const float theta = part + bin[q] + wv[q];
    const float c  = __cosf(theta);
    const float ca = __shfl_xor(c, 16, 64);   // cos of q^1
    const float cb = __shfl_xor(c, 32, 64);   // cos of q^2
    const float cd = __shfl_xor(ca, 32, 64);  // cos of q^3

    const float c0 = (q == 0) ? c : (q == 1) ? ca : (q == 2) ? cb : cd;
    const float c1 = (q == 1) ? c : (q == 0) ? ca : (q == 3) ? cb : cd;
    const float c2 = (q == 2) ? c : (q == 3) ? ca : (q == 0) ? cb : cd;
    const float c3 = (q == 3) ? c : (q == 2) ? ca : (q == 1) ? cb : cd;

    const float z0 = c1 * c2 * c3;
    const float z1 = c0 * c1;
    const float z2 = z1 * c2;
    const float z3 = z2 * c3;

    const float4 wo = *(const float4*)&Wout[lane * 4];
    const float out = z0 * wo.x + z1 * wo.y + z2 * wo.z + z3 * wo.w + bout[lane];
    dst[(((size_t)(b * H_ + h)) * S_ + s) * D_ + lane] = f2b(out);
}

// ---------------------------------------------------------------------------
// Kernel B: flash MFMA attention, NO max-tracking (softmax arg = S/32, tiny).
// Block = 64 q-rows of one (b,h), 4 waves x 16 rows, 8 chunks of 64 k-pos.
// ---------------------------------------------------------------------------
__global__ __launch_bounds__(256) void attn_kernel(
    const u16* __restrict__ Qb, const u16* __restrict__ Kb, const u16* __restrict__ Vb,
    u16* __restrict__ Ob)
{
    __shared__ __align__(16) u16 Ks[64][72];        // [kpos][d]
    __shared__ __align__(16) u16 Vt[64][72];        // [d][kpos] (transposed)
    __shared__ __align__(16) u16 Ps[4][16][80];     // per-wave P [qrow][kpos]

    const int t = threadIdx.x, lane = t & 63, w = t >> 6;
    const int bh = blockIdx.x >> 3;
    const int q0 = (blockIdx.x & 7) * 64;
    const int b = bh >> 3, h = bh & 7;

    const u16* Qp = Qb + (size_t)bh * (S_ * D_) + (size_t)q0 * D_;
    const u16* Kp = Kb + (size_t)bh * (S_ * D_);
    const u16* Vp = Vb + (size_t)bh * (S_ * D_);

    const int nl = lane & 15;           // n-index within 16x16 tile
    const int kg = (lane >> 4) * 8;     // k-group offset

    // Q fragments straight from global (coalesced 16B)
    const short8 qa0 = ld8(&Qp[(w * 16 + nl) * 64 + kg]);
    const short8 qa1 = ld8(&Qp[(w * 16 + nl) * 64 + kg + 32]);

    floatx4 of[4];
    float l_run[4] = {0.f, 0.f, 0.f, 0.f};
#pragma unroll
    for (int nt = 0; nt < 4; ++nt) of[nt] = 0.f;

    for (int ch = 0; ch < 8; ++ch) {
        __syncthreads();
        // stage K chunk [kpos][d]
        for (int i = t; i < 512; i += 256) {
            const int r = i & 63, c = (i >> 6) * 8;
            *(short8*)&Ks[r][c] = ld8(&Kp[(ch * 64 + r) * 64 + c]);
        }
        // stage V chunk transposed [d][kpos]
        for (int i = t; i < 512; i += 256) {
            const int r = i & 63, c = (i >> 6) * 8;
            short8 v = ld8(&Vp[(ch * 64 + r) * 64 + c]);
#pragma unroll
            for (int j = 0; j < 8; ++j) Vt[c + j][r] = (u16)((short*)&v)[j];
        }
        __syncthreads();

        // S = Q K^T
        floatx4 sf[4];
#pragma unroll
        for (int nt = 0; nt < 4; ++nt) sf[nt] = 0.f;
#pragma unroll
        for (int nt = 0; nt < 4; ++nt) {
            sf[nt] = __builtin_amdgcn_mfma_f32_16x16x32_bf16(qa0, ld8(&Ks[nt * 16 + nl][kg]), sf[nt], 0, 0, 0);
            sf[nt] = __builtin_amdgcn_mfma_f32_16x16x32_bf16(qa1, ld8(&Ks[nt * 16 + nl][kg + 32]), sf[nt], 0, 0, 0);
        }

        // P = exp(S/32), accumulate row-sum partials in registers
        const int prow = (lane >> 4) * 4;
#pragma unroll
        for (int nt = 0; nt < 4; ++nt) {
#pragma unroll
            for (int r = 0; r < 4; ++r) {
                const float pv = __expf(sf[nt][r] * 0.03125f);
                l_run[r] += pv;
                Ps[w][prow + r][nt * 16 + nl] = f2b(pv);
            }
        }

        // O += P V (same-wave LDS round-trip)
        const short8 pa0 = ld8(&Ps[w][nl][kg]);
        const short8 pa1 = ld8(&Ps[w][nl][kg + 32]);
#pragma unroll
        for (int nt = 0; nt < 4; ++nt) {
            of[nt] = __builtin_amdgcn_mfma_f32_16x16x32_bf16(pa0, ld8(&Vt[nt * 16 + nl][kg]), of[nt], 0, 0, 0);
            of[nt] = __builtin_amdgcn_mfma_f32_16x16x32_bf16(pa1, ld8(&Vt[nt * 16 + nl][kg + 32]), of[nt], 0, 0, 0);
        }
    }

    // final row-sum reduce (16 lanes share a row) + store O/l bf16 to (B,S,E)
    float inv[4];
#pragma unroll
    for (int r = 0; r < 4; ++r) {
        float sum = l_run[r];
#pragma unroll
        for (int off = 1; off < 16; off <<= 1) sum += __shfl_xor(sum, off, 64);
        inv[r] = 1.0f / sum;
    }
    const int srow = q0 + w * 16 + (lane >> 4) * 4;
#pragma unroll
    for (int r = 0; r < 4; ++r) {
        const size_t base = ((size_t)(b * S_ + srow + r)) * E_ + h * 64 + nl;
#pragma unroll
        for (int nt = 0; nt < 4; ++nt)
            Ob[base + nt * 16] = f2b(of[nt][r] * inv[r]);
    }
}

// ---------------------------------------------------------------------------
// Kernel C: out = [Qflat | O] @ Wo^T + bo  (8192x1024)x(1024x512), bf16 MFMA.
// 64x128 tile/block -> 512 blocks (2/CU).  2x2 waves of (32m x 64n).
// ---------------------------------------------------------------------------
__global__ __launch_bounds__(256) void out_kernel(
    const u16* __restrict__ Qb, const u16* __restrict__ Ob,
    const u16* __restrict__ Wb, const float* __restrict__ bo,
    float* __restrict__ out)
{
    __shared__ __align__(16) u16 As[64][72];    // cat rows [m][k]
    __shared__ __align__(16) u16 Bs[128][72];   // Wo rows  [n=e][k=j]

    const int t = threadIdx.x, lane = t & 63, w = t >> 6;
    const int e0 = (blockIdx.x & 3) * 128;
    const int n0 = (blockIdx.x >> 2) * 64;
    const int wr = (w >> 1) * 32, wc = (w & 1) * 64;
    const int nl = lane & 15, kg = (lane >> 4) * 8;

    floatx4 acc[2][4];
#pragma unroll
    for (int i = 0; i < 2; ++i)
#pragma unroll
        for (int j = 0; j < 4; ++j) acc[i][j] = 0.f;

    for (int j0 = 0; j0 < 1024; j0 += 64) {
        // stage A: cat[n0+r][j0+c]
        for (int i = t; i < 512; i += 256) {
            const int r = i & 63, c = (i >> 6) * 8;
            const int n = n0 + r;
            const u16* src = (j0 < 512)
                ? &Qb[(((size_t)(n >> 9) * 8 + (j0 >> 6)) * 512 + (n & 511)) * 64 + c]
                : &Ob[(size_t)n * 512 + (j0 - 512) + c];
            *(short8*)&As[r][c] = ld8(src);
        }
        // stage B: Wb[e0+r][j0+c] (already bf16)
        for (int i = t; i < 1024; i += 256) {
            const int r = i & 127, c = (i >> 7) * 8;
            *(short8*)&Bs[r][c] = ld8(&Wb[(size_t)(e0 + r) * 1024 + j0 + c]);
        }
        __syncthreads();

        short8 af[2][2], bfr[4][2];
#pragma unroll
        for (int mt = 0; mt < 2; ++mt) {
            af[mt][0] = ld8(&As[wr + mt * 16 + nl][kg]);
            af[mt][1] = ld8(&As[wr + mt * 16 + nl][kg + 32]);
        }
#pragma unroll
        for (int nt = 0; nt < 4; ++nt) {
            bfr[nt][0] = ld8(&Bs[wc + nt * 16 + nl][kg]);
            bfr[nt][1] = ld8(&Bs[wc + nt * 16 + nl][kg + 32]);
        }
#pragma unroll
        for (int mt = 0; mt < 2; ++mt)
#pragma unroll
            for (int nt = 0; nt < 4; ++nt) {
                acc[mt][nt] = __builtin_amdgcn_mfma_f32_16x16x32_bf16(af[mt][0], bfr[nt][0], acc[mt][nt], 0, 0, 0);
                acc[mt][nt] = __builtin_amdgcn_mfma_f32_16x16x32_bf16(af[mt][1], bfr[nt][1], acc[mt][nt], 0, 0, 0);
            }
        __syncthreads();
    }

    const int prow = (lane >> 4) * 4;
#pragma unroll
    for (int mt = 0; mt < 2; ++mt)
#pragma unroll
        for (int r = 0; r < 4; ++r) {
            const int n = n0 + wr + mt * 16 + prow + r;
#pragma unroll
            for (int nt = 0; nt < 4; ++nt) {
                const int e = e0 + wc + nt * 16 + nl;
                out[(size_t)n * 512 + e] = acc[mt][nt][r] + bo[e];
            }
        }
}

// ---------------------------------------------------------------------------
extern "C" void kernel_launch(void* const* d_in, const int* in_sizes, int n_in,
                              void* d_out, int out_size, void* d_ws, size_t ws_size,
                              hipStream_t stream)
{
    const float* q_in  = (const float*)d_in[0];
    const float* k_in  = (const float*)d_in[1];
    const float* v_in  = (const float*)d_in[2];
    // d_in[3] = mask (int32) — semantic no-op in the reference
    const float* Wq_in = (const float*)d_in[4];
    const float* bq_in = (const float*)d_in[5];
    const float* Wk_in = (const float*)d_in[6];
    const float* bk_in = (const float*)d_in[7];
    const float* Wv_in = (const float*)d_in[8];
    const float* bv_in = (const float*)d_in[9];
    const float* wvq   = (const float*)d_in[10];
    const float* wvk   = (const float*)d_in[11];
    const float* wvv   = (const float*)d_in[12];
    const float* Wq    = (const float*)d_in[13];
    const float* bq    = (const float*)d_in[14];
    const float* Wk    = (const float*)d_in[15];
    const float* bk    = (const float*)d_in[16];
    const float* Wv    = (const float*)d_in[17];
    const float* bv    = (const float*)d_in[18];
    const float* Wo    = (const float*)d_in[19];
    const float* bo    = (const float*)d_in[20];

    u16* ws = (u16*)d_ws;
    u16* Qb = ws;                          // (B,H,S,D) bf16, 4M elems
    u16* Kb = ws + (size_t)(1 << 22);
    u16* Vb = ws + (size_t)(2 << 22);
    u16* Ob = ws + (size_t)3 * (1 << 22);  // (B,S,E) bf16
    u16* Wb = ws + (size_t)4 * (1 << 22);  // Wo bf16, 512K elems

    wconv_kernel<<<256, 256, 0, stream>>>(Wo, Wb);
    proj_kernel<<<49152, 256, 0, stream>>>(q_in, k_in, v_in,
        Wq_in, bq_in, Wk_in, bk_in, Wv_in, bv_in,
        wvq, wvk, wvv, Wq, bq, Wk, bk, Wv, bv,
        Qb, Kb, Vb);
    attn_kernel<<<1024, 256, 0, stream>>>(Qb, Kb, Vb, Ob);
    out_kernel<<<512, 256, 0, stream>>>(Qb, Ob, Wb, bo, (float*)d_out);
}

// Round 5
// 225.929 us; speedup vs baseline: 4.0426x; 1.0239x over previous
//
#include <hip/hip_runtime.h>
#include <hip/hip_bf16.h>

#define B_ 16
#define S_ 512
#define E_ 512
#define H_ 8
#define D_ 64

typedef __hip_bfloat16 bf16;
typedef unsigned short u16;
typedef __attribute__((ext_vector_type(8))) short short8;
typedef __attribute__((ext_vector_type(4))) float floatx4;

__device__ __forceinline__ u16 f2b(float x) {
    bf16 h = __float2bfloat16(x);
    return *reinterpret_cast<u16*>(&h);
}
__device__ __forceinline__ short8 ld8(const u16* p) { return *(const short8*)p; }

#define PROJ_BLOCKS 49152

// ---------------------------------------------------------------------------
// Kernel A: quantum projections (closed-form VQC).  One wave per (proj,b,s,h).
// lane = (q = lane>>4, dsub = lane&15): float4 partial dot, 4-level reduce,
// ONE __cosf, then broadcast the 4 group-uniform cosines via __shfl and form
//   Z0=c1c2c3, Z1=c0c1, Z2=c0c1c2, Z3=c0c1c2c3   with 5 multiplies.
// Q/K/V written bf16 in (B,H,S,D).
// Blocks >= PROJ_BLOCKS instead convert Wo fp32 -> bf16 (grid-fused wconv).
// ---------------------------------------------------------------------------
__global__ __launch_bounds__(256) void proj_kernel(
    const float* __restrict__ q_in, const float* __restrict__ k_in, const float* __restrict__ v_in,
    const float* __restrict__ Wq_in, const float* __restrict__ bq_in,
    const float* __restrict__ Wk_in, const float* __restrict__ bk_in,
    const float* __restrict__ Wv_in, const float* __restrict__ bv_in,
    const float* __restrict__ wvq, const float* __restrict__ wvk, const float* __restrict__ wvv,
    const float* __restrict__ Wq, const float* __restrict__ bq,
    const float* __restrict__ Wk, const float* __restrict__ bk,
    const float* __restrict__ Wv, const float* __restrict__ bv,
    const float* __restrict__ Wo, u16* __restrict__ Wb,
    u16* __restrict__ Qb, u16* __restrict__ Kb, u16* __restrict__ Vb)
{
    if (blockIdx.x >= PROJ_BLOCKS) {
        // fused Wo fp32 -> bf16 (512x1024 = 524288 elems, 256 blocks x 256 x 8)
        const int i = ((blockIdx.x - PROJ_BLOCKS) * 256 + threadIdx.x) * 8;
        const float4 a = *(const float4*)&Wo[i];
        const float4 b4 = *(const float4*)&Wo[i + 4];
        u16 tmp[8] __attribute__((aligned(16)));
        tmp[0] = f2b(a.x); tmp[1] = f2b(a.y); tmp[2] = f2b(a.z); tmp[3] = f2b(a.w);
        tmp[4] = f2b(b4.x); tmp[5] = f2b(b4.y); tmp[6] = f2b(b4.z); tmp[7] = f2b(b4.w);
        *(short8*)&Wb[i] = *(short8*)tmp;
        return;
    }

    const int wave = threadIdx.x >> 6;
    const int lane = threadIdx.x & 63;
    const int g = blockIdx.x * 4 + wave;          // 3*65536 groups
    const int p = g >> 16;
    const int m = g & 0xFFFF;                     // b*4096 + s*8 + h
    const int h = m & 7;
    const int s = (m >> 3) & 511;
    const int b = m >> 12;

    const float *X, *Win, *bin, *wv, *Wout, *bout;
    u16* dst;
    if (p == 0)      { X = q_in; Win = Wq_in; bin = bq_in; wv = wvq; Wout = Wq; bout = bq; dst = Qb; }
    else if (p == 1) { X = k_in; Win = Wk_in; bin = bk_in; wv = wvk; Wout = Wk; bout = bk; dst = Kb; }
    else             { X = v_in; Win = Wv_in; bin = bv_in; wv = wvv; Wout = Wv; bout = bv; dst = Vb; }

    const int q = lane >> 4;
    const int dsub = lane & 15;

    const float4 x4 = *(const float4*)(X + ((size_t)(b * S_ + s)) * E_ + h * 64 + dsub * 4);
    const float4 w4 = *(const float4*)(Win + q * 64 + dsub * 4);

    float part = x4.x * w4.x + x4.y * w4.y + x4.z * w4.z + x4.w * w4.w;
#pragma unroll
    for (int off = 8; off >= 1; off >>= 1)
        part += __shfl_xor(part, off, 64);

    const float theta = part + bin[q] + wv[q];
    const float c = __cosf(theta);

    // group-uniform broadcasts (each 16-lane group holds one cosine)
    const float c0 = __shfl(c, 0, 64);
    const float c1 = __shfl(c, 16, 64);
    const float c2 = __shfl(c, 32, 64);
    const float c3 = __shfl(c, 48, 64);

    const float tt = c2 * c3;
    const float z1 = c0 * c1;
    const float z0 = c1 * tt;
    const float z2 = z1 * c2;
    const float z3 = z1 * tt;

    const float4 wo = *(const float4*)&Wout[lane * 4];
    const float out = fmaf(z0, wo.x, fmaf(z1, wo.y, fmaf(z2, wo.z, fmaf(z3, wo.w, bout[lane]))));
    dst[(((size_t)(b * H_ + h)) * S_ + s) * D_ + lane] = f2b(out);
}

// ---------------------------------------------------------------------------
// Kernel B: flash MFMA attention, NO max-tracking (softmax arg = S/32, tiny).
// Block = 64 q-rows of one (b,h), 4 waves x 16 rows, 8 chunks of 64 k-pos.
// ---------------------------------------------------------------------------
__global__ __launch_bounds__(256) void attn_kernel(
    const u16* __restrict__ Qb, const u16* __restrict__ Kb, const u16* __restrict__ Vb,
    u16* __restrict__ Ob)
{
    __shared__ __align__(16) u16 Ks[64][72];        // [kpos][d]
    __shared__ __align__(16) u16 Vt[64][72];        // [d][kpos] (transposed)
    __shared__ __align__(16) u16 Ps[4][16][72];     // per-wave P [qrow][kpos]

    const int t = threadIdx.x, lane = t & 63, w = t >> 6;
    const int bh = blockIdx.x >> 3;
    const int q0 = (blockIdx.x & 7) * 64;
    const int b = bh >> 3, h = bh & 7;

    const u16* Qp = Qb + (size_t)bh * (S_ * D_) + (size_t)q0 * D_;
    const u16* Kp = Kb + (size_t)bh * (S_ * D_);
    const u16* Vp = Vb + (size_t)bh * (S_ * D_);

    const int nl = lane & 15;           // n-index within 16x16 tile
    const int kg = (lane >> 4) * 8;     // k-group offset

    // Q fragments straight from global (coalesced 16B)
    const short8 qa0 = ld8(&Qp[(w * 16 + nl) * 64 + kg]);
    const short8 qa1 = ld8(&Qp[(w * 16 + nl) * 64 + kg + 32]);

    floatx4 of[4];
    float l_run[4] = {0.f, 0.f, 0.f, 0.f};
#pragma unroll
    for (int nt = 0; nt < 4; ++nt) of[nt] = 0.f;

    // V-transpose staging coords: 2 rows x 8 cols per thread
    const int vr0 = (t & 31) * 2, vc = (t >> 5) * 8;

    for (int ch = 0; ch < 8; ++ch) {
        __syncthreads();
        // stage K chunk [kpos][d]
        for (int i = t; i < 512; i += 256) {
            const int r = i & 63, c = (i >> 6) * 8;
            *(short8*)&Ks[r][c] = ld8(&Kp[(ch * 64 + r) * 64 + c]);
        }
        // stage V chunk transposed [d][kpos], pair-packed dword writes
        {
            short8 va = ld8(&Vp[(ch * 64 + vr0) * 64 + vc]);
            short8 vb = ld8(&Vp[(ch * 64 + vr0 + 1) * 64 + vc]);
#pragma unroll
            for (int j = 0; j < 8; ++j) {
                const unsigned pack = (u16)((short*)&va)[j] |
                                      ((unsigned)(u16)((short*)&vb)[j] << 16);
                *(unsigned*)&Vt[vc + j][vr0] = pack;
            }
        }
        __syncthreads();

        // S = Q K^T
        floatx4 sf[4];
#pragma unroll
        for (int nt = 0; nt < 4; ++nt) sf[nt] = 0.f;
#pragma unroll
        for (int nt = 0; nt < 4; ++nt) {
            sf[nt] = __builtin_amdgcn_mfma_f32_16x16x32_bf16(qa0, ld8(&Ks[nt * 16 + nl][kg]), sf[nt], 0, 0, 0);
            sf[nt] = __builtin_amdgcn_mfma_f32_16x16x32_bf16(qa1, ld8(&Ks[nt * 16 + nl][kg + 32]), sf[nt], 0, 0, 0);
        }

        // P = exp(S/32), accumulate row-sum partials in registers
        const int prow = (lane >> 4) * 4;
#pragma unroll
        for (int nt = 0; nt < 4; ++nt) {
#pragma unroll
            for (int r = 0; r < 4; ++r) {
                const float pv = __expf(sf[nt][r] * 0.03125f);
                l_run[r] += pv;
                Ps[w][prow + r][nt * 16 + nl] = f2b(pv);
            }
        }

        // O += P V (same-wave LDS round-trip)
        const short8 pa0 = ld8(&Ps[w][nl][kg]);
        const short8 pa1 = ld8(&Ps[w][nl][kg + 32]);
#pragma unroll
        for (int nt = 0; nt < 4; ++nt) {
            of[nt] = __builtin_amdgcn_mfma_f32_16x16x32_bf16(pa0, ld8(&Vt[nt * 16 + nl][kg]), of[nt], 0, 0, 0);
            of[nt] = __builtin_amdgcn_mfma_f32_16x16x32_bf16(pa1, ld8(&Vt[nt * 16 + nl][kg + 32]), of[nt], 0, 0, 0);
        }
    }

    // final row-sum reduce (16 lanes share a row) + store O/l bf16 to (B,S,E)
    float inv[4];
#pragma unroll
    for (int r = 0; r < 4; ++r) {
        float sum = l_run[r];
#pragma unroll
        for (int off = 1; off < 16; off <<= 1) sum += __shfl_xor(sum, off, 64);
        inv[r] = 1.0f / sum;
    }
    const int srow = q0 + w * 16 + (lane >> 4) * 4;
#pragma unroll
    for (int r = 0; r < 4; ++r) {
        const size_t base = ((size_t)(b * S_ + srow + r)) * E_ + h * 64 + nl;
#pragma unroll
        for (int nt = 0; nt < 4; ++nt)
            Ob[base + nt * 16] = f2b(of[nt][r] * inv[r]);
    }
}

// ---------------------------------------------------------------------------
// Kernel C: out = [Qflat | O] @ Wo^T + bo  (8192x1024)x(1024x512), bf16 MFMA.
// 64x128 tile/block -> 512 blocks (2/CU).  2x2 waves of (32m x 64n).
// ---------------------------------------------------------------------------
__global__ __launch_bounds__(256) void out_kernel(
    const u16* __restrict__ Qb, const u16* __restrict__ Ob,
    const u16* __restrict__ Wb, const float* __restrict__ bo,
    float* __restrict__ out)
{
    __shared__ __align__(16) u16 As[64][72];    // cat rows [m][k]
    __shared__ __align__(16) u16 Bs[128][72];   // Wo rows  [n=e][k=j]

    const int t = threadIdx.x, lane = t & 63, w = t >> 6;
    const int e0 = (blockIdx.x & 3) * 128;
    const int n0 = (blockIdx.x >> 2) * 64;
    const int wr = (w >> 1) * 32, wc = (w & 1) * 64;
    const int nl = lane & 15, kg = (lane >> 4) * 8;

    floatx4 acc[2][4];
#pragma unroll
    for (int i = 0; i < 2; ++i)
#pragma unroll
        for (int j = 0; j < 4; ++j) acc[i][j] = 0.f;

    for (int j0 = 0; j0 < 1024; j0 += 64) {
        // stage A: cat[n0+r][j0+c]
        for (int i = t; i < 512; i += 256) {
            const int r = i & 63, c = (i >> 6) * 8;
            const int n = n0 + r;
            const u16* src = (j0 < 512)
                ? &Qb[(((size_t)(n >> 9) * 8 + (j0 >> 6)) * 512 + (n & 511)) * 64 + c]
                : &Ob[(size_t)n * 512 + (j0 - 512) + c];
            *(short8*)&As[r][c] = ld8(src);
        }
        // stage B: Wb[e0+r][j0+c] (already bf16)
        for (int i = t; i < 1024; i += 256) {
            const int r = i & 127, c = (i >> 7) * 8;
            *(short8*)&Bs[r][c] = ld8(&Wb[(size_t)(e0 + r) * 1024 + j0 + c]);
        }
        __syncthreads();

        short8 af[2][2], bfr[4][2];
#pragma unroll
        for (int mt = 0; mt < 2; ++mt) {
            af[mt][0] = ld8(&As[wr + mt * 16 + nl][kg]);
            af[mt][1] = ld8(&As[wr + mt * 16 + nl][kg + 32]);
        }
#pragma unroll
        for (int nt = 0; nt < 4; ++nt) {
            bfr[nt][0] = ld8(&Bs[wc + nt * 16 + nl][kg]);
            bfr[nt][1] = ld8(&Bs[wc + nt * 16 + nl][kg + 32]);
        }
#pragma unroll
        for (int mt = 0; mt < 2; ++mt)
#pragma unroll
            for (int nt = 0; nt < 4; ++nt) {
                acc[mt][nt] = __builtin_amdgcn_mfma_f32_16x16x32_bf16(af[mt][0], bfr[nt][0], acc[mt][nt], 0, 0, 0);
                acc[mt][nt] = __builtin_amdgcn_mfma_f32_16x16x32_bf16(af[mt][1], bfr[nt][1], acc[mt][nt], 0, 0, 0);
            }
        __syncthreads();
    }

    const int prow = (lane >> 4) * 4;
#pragma unroll
    for (int mt = 0; mt < 2; ++mt)
#pragma unroll
        for (int r = 0; r < 4; ++r) {
            const int n = n0 + wr + mt * 16 + prow + r;
#pragma unroll
            for (int nt = 0; nt < 4; ++nt) {
                const int e = e0 + wc + nt * 16 + nl;
                out[(size_t)n * 512 + e] = acc[mt][nt][r] + bo[e];
            }
        }
}

// ---------------------------------------------------------------------------
extern "C" void kernel_launch(void* const* d_in, const int* in_sizes, int n_in,
                              void* d_out, int out_size, void* d_ws, size_t ws_size,
                              hipStream_t stream)
{
    const float* q_in  = (const float*)d_in[0];
    const float* k_in  = (const float*)d_in[1];
    const float* v_in  = (const float*)d_in[2];
    // d_in[3] = mask (int32) — semantic no-op in the reference
    const float* Wq_in = (const float*)d_in[4];
    const float* bq_in = (const float*)d_in[5];
    const float* Wk_in = (const float*)d_in[6];
    const float* bk_in = (const float*)d_in[7];
    const float* Wv_in = (const float*)d_in[8];
    const float* bv_in = (const float*)d_in[9];
    const float* wvq   = (const float*)d_in[10];
    const float* wvk   = (const float*)d_in[11];
    const float* wvv   = (const float*)d_in[12];
    const float* Wq    = (const float*)d_in[13];
    const float* bq    = (const float*)d_in[14];
    const float* Wk    = (const float*)d_in[15];
    const float* bk    = (const float*)d_in[16];
    const float* Wv    = (const float*)d_in[17];
    const float* bv    = (const float*)d_in[18];
    const float* Wo    = (const float*)d_in[19];
    const float* bo    = (const float*)d_in[20];

    u16* ws = (u16*)d_ws;
    u16* Qb = ws;                          // (B,H,S,D) bf16, 4M elems
    u16* Kb = ws + (size_t)(1 << 22);
    u16* Vb = ws + (size_t)(2 << 22);
    u16* Ob = ws + (size_t)3 * (1 << 22);  // (B,S,E) bf16
    u16* Wb = ws + (size_t)4 * (1 << 22);  // Wo bf16, 512K elems

    proj_kernel<<<PROJ_BLOCKS + 256, 256, 0, stream>>>(q_in, k_in, v_in,
        Wq_in, bq_in, Wk_in, bk_in, Wv_in, bv_in,
        wvq, wvk, wvv, Wq, bq, Wk, bk, Wv, bv,
        Wo, Wb, Qb, Kb, Vb);
    attn_kernel<<<1024, 256, 0, stream>>>(Qb, Kb, Vb, Ob);
    out_kernel<<<512, 256, 0, stream>>>(Qb, Ob, Wb, bo, (float*)d_out);
}

// Round 7
// 190.265 us; speedup vs baseline: 4.8003x; 1.1874x over previous
//
#include <hip/hip_runtime.h>
#include <hip/hip_bf16.h>

#define B_ 16
#define S_ 512
#define E_ 512
#define H_ 8
#define D_ 64

typedef __hip_bfloat16 bf16;
typedef unsigned short u16;
typedef __attribute__((ext_vector_type(8))) short short8;
typedef __attribute__((ext_vector_type(4))) float floatx4;

__device__ __forceinline__ u16 f2b(float x) {
    bf16 h = __float2bfloat16(x);
    return *reinterpret_cast<u16*>(&h);
}
__device__ __forceinline__ short8 ld8(const u16* p) { return *(const short8*)p; }

// quad_perm DPP xor within groups of 4 lanes (pure VALU, no LDS)
template<int CTRL>
__device__ __forceinline__ float qperm(float x) {
    return __builtin_bit_cast(float,
        __builtin_amdgcn_update_dpp(0, __builtin_bit_cast(int, x), CTRL, 0xF, 0xF, true));
}

#define PROJ_ROW_BLOCKS 3072   // 3 proj x 65536 rows / 64 rows-per-block

// ---------------------------------------------------------------------------
// Kernel A: quantum projections (closed-form VQC), quad-per-row layout.
// 4 lanes own one (b,s,h) row; lane j handles d in [16j,16j+16).
//  - X offset is exactly 64*m (linear streaming, float4 loads)
//  - weights staged in LDS once/block; all reads are broadcast
//  - quad dot-reduce via 2 DPP quad_perm ops
//  - Z0=c1c2c3, Z1=c0c1, Z2=c0c1c2, Z3=c0c1c2c3; out = Z·Wout^T + bout
// Q/K/V written bf16 in (B,H,S,D).  Tail blocks convert Wo fp32->bf16.
// ---------------------------------------------------------------------------
__global__ __launch_bounds__(256) void proj_kernel(
    const float* __restrict__ q_in, const float* __restrict__ k_in, const float* __restrict__ v_in,
    const float* __restrict__ Wq_in, const float* __restrict__ bq_in,
    const float* __restrict__ Wk_in, const float* __restrict__ bk_in,
    const float* __restrict__ Wv_in, const float* __restrict__ bv_in,
    const float* __restrict__ wvq, const float* __restrict__ wvk, const float* __restrict__ wvv,
    const float* __restrict__ Wq, const float* __restrict__ bq,
    const float* __restrict__ Wk, const float* __restrict__ bk,
    const float* __restrict__ Wv, const float* __restrict__ bv,
    const float* __restrict__ Wo, u16* __restrict__ Wb,
    u16* __restrict__ Qb, u16* __restrict__ Kb, u16* __restrict__ Vb)
{
    if (blockIdx.x >= PROJ_ROW_BLOCKS) {
        // fused Wo fp32 -> bf16 (524288 elems, 256 blocks x 256 threads x 8)
        const int i = ((blockIdx.x - PROJ_ROW_BLOCKS) * 256 + threadIdx.x) * 8;
        const float4 a = *(const float4*)&Wo[i];
        const float4 b4 = *(const float4*)&Wo[i + 4];
        u16 tmp[8] __attribute__((aligned(16)));
        tmp[0] = f2b(a.x); tmp[1] = f2b(a.y); tmp[2] = f2b(a.z); tmp[3] = f2b(a.w);
        tmp[4] = f2b(b4.x); tmp[5] = f2b(b4.y); tmp[6] = f2b(b4.z); tmp[7] = f2b(b4.w);
        *(short8*)&Wb[i] = *(short8*)tmp;
        return;
    }

    __shared__ __align__(16) float sWin[256];    // [q][d]  (4 x 64)
    __shared__ __align__(16) float sWout[256];   // [d][q]  (64 x 4)
    __shared__ __align__(16) float sbout[64];
    __shared__ float4 sbw;                       // bin + wv (aligned)

    const int t = threadIdx.x;
    const int p = blockIdx.x >> 10;           // projection 0/1/2

    const float *X, *Win, *bin, *wv, *Wout, *bout;
    u16* dst;
    if (p == 0)      { X = q_in; Win = Wq_in; bin = bq_in; wv = wvq; Wout = Wq; bout = bq; dst = Qb; }
    else if (p == 1) { X = k_in; Win = Wk_in; bin = bk_in; wv = wvk; Wout = Wk; bout = bk; dst = Kb; }
    else             { X = v_in; Win = Wv_in; bin = bv_in; wv = wvv; Wout = Wv; bout = bv; dst = Vb; }

    sWin[t] = Win[t];
    sWout[t] = Wout[t];
    if (t < 64) sbout[t] = bout[t];
    if (t == 0) sbw = make_float4(bin[0] + wv[0], bin[1] + wv[1],
                                  bin[2] + wv[2], bin[3] + wv[3]);
    __syncthreads();

    const int j = t & 3;                       // d-quarter within row
    const int m = (blockIdx.x & 1023) * 64 + (t >> 2);   // row = b*4096 + s*8 + h
    const int d0 = j * 16;

    // ---- dot phase: part[q] over my 16 d's, then quad reduce via DPP
    const float* xp = X + (size_t)m * 64 + d0;
    float4 xv[4];
#pragma unroll
    for (int i = 0; i < 4; ++i) xv[i] = *(const float4*)(xp + i * 4);

    float part[4] = {0.f, 0.f, 0.f, 0.f};
#pragma unroll
    for (int i = 0; i < 4; ++i) {
#pragma unroll
        for (int q = 0; q < 4; ++q) {
            const float4 w4 = *(const float4*)&sWin[q * 64 + d0 + i * 4];
            part[q] = fmaf(xv[i].x, w4.x, fmaf(xv[i].y, w4.y,
                      fmaf(xv[i].z, w4.z, fmaf(xv[i].w, w4.w, part[q]))));
        }
    }
#pragma unroll
    for (int q = 0; q < 4; ++q) {
        part[q] += qperm<0xB1>(part[q]);   // xor 1
        part[q] += qperm<0x4E>(part[q]);   // xor 2
    }

    const float4 bw = sbw;
    const float c0 = __cosf(part[0] + bw.x);
    const float c1 = __cosf(part[1] + bw.y);
    const float c2 = __cosf(part[2] + bw.z);
    const float c3 = __cosf(part[3] + bw.w);
    const float tt = c2 * c3;
    const float z1 = c0 * c1;
    const float z0 = c1 * tt;
    const float z2 = z1 * c2;
    const float z3 = z1 * tt;

    // ---- output phase: my 16 d's
    const int b = m >> 12, s = (m >> 3) & 511, h = m & 7;
    u16* op = dst + ((size_t)(b * 4096 + h * 512 + s)) * 64 + d0;

    u16 tmp[16] __attribute__((aligned(16)));
#pragma unroll
    for (int d = 0; d < 16; ++d) {
        const float4 wo = *(const float4*)&sWout[(d0 + d) * 4];
        const float o = fmaf(z0, wo.x, fmaf(z1, wo.y,
                        fmaf(z2, wo.z, fmaf(z3, wo.w, sbout[d0 + d]))));
        tmp[d] = f2b(o);
    }
    *(short8*)op = *(short8*)tmp;
    *(short8*)(op + 8) = *(short8*)(tmp + 8);
}

// ---------------------------------------------------------------------------
// Kernel B: flash MFMA attention, NO max-tracking (softmax arg = S/32, tiny).
// Block = 64 q-rows of one (b,h), 4 waves x 16 rows, 8 chunks of 64 k-pos.
// Global K/V loads for chunk ch+1 prefetched into regs during chunk ch.
// ---------------------------------------------------------------------------
__global__ __launch_bounds__(256) void attn_kernel(
    const u16* __restrict__ Qb, const u16* __restrict__ Kb, const u16* __restrict__ Vb,
    u16* __restrict__ Ob)
{
    __shared__ __align__(16) u16 Ks[64][72];        // [kpos][d]
    __shared__ __align__(16) u16 Vt[64][72];        // [d][kpos] (transposed)
    __shared__ __align__(16) u16 Ps[4][16][72];     // per-wave P [qrow][kpos]

    const int t = threadIdx.x, lane = t & 63, w = t >> 6;
    const int bh = blockIdx.x >> 3;
    const int q0 = (blockIdx.x & 7) * 64;
    const int b = bh >> 3, h = bh & 7;

    const u16* Qp = Qb + (size_t)bh * (S_ * D_) + (size_t)q0 * D_;
    const u16* Kp = Kb + (size_t)bh * (S_ * D_);
    const u16* Vp = Vb + (size_t)bh * (S_ * D_);

    const int nl = lane & 15;           // n-index within 16x16 tile
    const int kg = (lane >> 4) * 8;     // k-group offset

    // Q fragments straight from global (coalesced 16B)
    const short8 qa0 = ld8(&Qp[(w * 16 + nl) * 64 + kg]);
    const short8 qa1 = ld8(&Qp[(w * 16 + nl) * 64 + kg + 32]);

    floatx4 of[4];
    float l_run[4] = {0.f, 0.f, 0.f, 0.f};
#pragma unroll
    for (int nt = 0; nt < 4; ++nt) of[nt] = 0.f;

    // staging coords
    const int rK = t & 63, cK = (t >> 6) * 8;            // K: 2 vectors (cK, cK+32)
    const int vr0 = (t & 31) * 2, vc = (t >> 5) * 8;     // V: rows vr0, vr0+1 at col vc

    // prefetch chunk 0
    short8 kA = ld8(&Kp[rK * 64 + cK]);
    short8 kB = ld8(&Kp[rK * 64 + cK + 32]);
    short8 vA = ld8(&Vp[vr0 * 64 + vc]);
    short8 vB = ld8(&Vp[(vr0 + 1) * 64 + vc]);

    for (int ch = 0; ch < 8; ++ch) {
        __syncthreads();
        // write staged chunk to LDS
        *(short8*)&Ks[rK][cK] = kA;
        *(short8*)&Ks[rK][cK + 32] = kB;
#pragma unroll
        for (int jj = 0; jj < 8; ++jj) {
            const unsigned pack = (u16)((short*)&vA)[jj] |
                                  ((unsigned)(u16)((short*)&vB)[jj] << 16);
            *(unsigned*)&Vt[vc + jj][vr0] = pack;
        }
        // prefetch next chunk (latency hidden behind this chunk's compute)
        if (ch < 7) {
            const int nb = (ch + 1) * 64;
            kA = ld8(&Kp[(nb + rK) * 64 + cK]);
            kB = ld8(&Kp[(nb + rK) * 64 + cK + 32]);
            vA = ld8(&Vp[(nb + vr0) * 64 + vc]);
            vB = ld8(&Vp[(nb + vr0 + 1) * 64 + vc]);
        }
        __syncthreads();

        // S = Q K^T
        floatx4 sf[4];
#pragma unroll
        for (int nt = 0; nt < 4; ++nt) sf[nt] = 0.f;
#pragma unroll
        for (int nt = 0; nt < 4; ++nt) {
            sf[nt] = __builtin_amdgcn_mfma_f32_16x16x32_bf16(qa0, ld8(&Ks[nt * 16 + nl][kg]), sf[nt], 0, 0, 0);
            sf[nt] = __builtin_amdgcn_mfma_f32_16x16x32_bf16(qa1, ld8(&Ks[nt * 16 + nl][kg + 32]), sf[nt], 0, 0, 0);
        }

        // P = exp(S/32), accumulate row-sum partials in registers
        const int prow = (lane >> 4) * 4;
#pragma unroll
        for (int nt = 0; nt < 4; ++nt) {
#pragma unroll
            for (int r = 0; r < 4; ++r) {
                const float pv = __expf(sf[nt][r] * 0.03125f);
                l_run[r] += pv;
                Ps[w][prow + r][nt * 16 + nl] = f2b(pv);
            }
        }

        // O += P V (same-wave LDS round-trip)
        const short8 pa0 = ld8(&Ps[w][nl][kg]);
        const short8 pa1 = ld8(&Ps[w][nl][kg + 32]);
#pragma unroll
        for (int nt = 0; nt < 4; ++nt) {
            of[nt] = __builtin_amdgcn_mfma_f32_16x16x32_bf16(pa0, ld8(&Vt[nt * 16 + nl][kg]), of[nt], 0, 0, 0);
            of[nt] = __builtin_amdgcn_mfma_f32_16x16x32_bf16(pa1, ld8(&Vt[nt * 16 + nl][kg + 32]), of[nt], 0, 0, 0);
        }
    }

    // final row-sum reduce (16 lanes share a row) + store O/l bf16 to (B,S,E)
    float inv[4];
#pragma unroll
    for (int r = 0; r < 4; ++r) {
        float sum = l_run[r];
#pragma unroll
        for (int off = 1; off < 16; off <<= 1) sum += __shfl_xor(sum, off, 64);
        inv[r] = 1.0f / sum;
    }
    const int srow = q0 + w * 16 + (lane >> 4) * 4;
#pragma unroll
    for (int r = 0; r < 4; ++r) {
        const size_t base = ((size_t)(b * S_ + srow + r)) * E_ + h * 64 + nl;
#pragma unroll
        for (int nt = 0; nt < 4; ++nt)
            Ob[base + nt * 16] = f2b(of[nt][r] * inv[r]);
    }
}

// ---------------------------------------------------------------------------
// Kernel C: out = [Qflat | O] @ Wo^T + bo  (8192x1024)x(1024x512), bf16 MFMA.
// 64x128 tile/block -> 512 blocks (2/CU).  2x2 waves of (32m x 64n).
// Next K-slab's global loads prefetched into regs during current slab.
// B staging: 4 vectors/thread (cB0, +16, +32, +48) = FULL 64-col coverage.
// ---------------------------------------------------------------------------
__global__ __launch_bounds__(256) void out_kernel(
    const u16* __restrict__ Qb, const u16* __restrict__ Ob,
    const u16* __restrict__ Wb, const float* __restrict__ bo,
    float* __restrict__ out)
{
    __shared__ __align__(16) u16 As[64][72];    // cat rows [m][k]
    __shared__ __align__(16) u16 Bs[128][72];   // Wo rows  [n=e][k=j]

    const int t = threadIdx.x, lane = t & 63, w = t >> 6;
    const int e0 = (blockIdx.x & 3) * 128;
    const int n0 = (blockIdx.x >> 2) * 64;
    const int wr = (w >> 1) * 32, wc = (w & 1) * 64;
    const int nl = lane & 15, kg = (lane >> 4) * 8;

    // staging coords
    const int rA = t & 63, cA = (t >> 6) * 8;        // A: 2 vectors (cA, cA+32)
    const int rB = t & 127, cB0 = (t >> 7) * 8;      // B: 4 vectors (cB0,+16,+32,+48)
    const u16* wrow = &Wb[(size_t)(e0 + rB) * 1024];

    floatx4 acc[2][4];
#pragma unroll
    for (int i = 0; i < 2; ++i)
#pragma unroll
        for (int jq = 0; jq < 4; ++jq) acc[i][jq] = 0.f;

    auto a_src = [&](int j0, int r, int c) -> const u16* {
        const int n = n0 + r;
        return (j0 < 512)
            ? &Qb[(((size_t)(n >> 9) * 8 + (j0 >> 6)) * 512 + (n & 511)) * 64 + c]
            : &Ob[(size_t)n * 512 + (j0 - 512) + c];
    };

    // prefetch slab 0
    short8 aA = ld8(a_src(0, rA, cA));
    short8 aB = ld8(a_src(0, rA, cA + 32));
    short8 b0 = ld8(wrow + cB0);
    short8 b1 = ld8(wrow + cB0 + 16);
    short8 b2 = ld8(wrow + cB0 + 32);
    short8 b3 = ld8(wrow + cB0 + 48);

    for (int j0 = 0; j0 < 1024; j0 += 64) {
        __syncthreads();
        *(short8*)&As[rA][cA] = aA;
        *(short8*)&As[rA][cA + 32] = aB;
        *(short8*)&Bs[rB][cB0] = b0;
        *(short8*)&Bs[rB][cB0 + 16] = b1;
        *(short8*)&Bs[rB][cB0 + 32] = b2;
        *(short8*)&Bs[rB][cB0 + 48] = b3;
        if (j0 < 960) {
            const int jn = j0 + 64;
            aA = ld8(a_src(jn, rA, cA));
            aB = ld8(a_src(jn, rA, cA + 32));
            b0 = ld8(wrow + jn + cB0);
            b1 = ld8(wrow + jn + cB0 + 16);
            b2 = ld8(wrow + jn + cB0 + 32);
            b3 = ld8(wrow + jn + cB0 + 48);
        }
        __syncthreads();

        short8 af[2][2], bfr[4][2];
#pragma unroll
        for (int mt = 0; mt < 2; ++mt) {
            af[mt][0] = ld8(&As[wr + mt * 16 + nl][kg]);
            af[mt][1] = ld8(&As[wr + mt * 16 + nl][kg + 32]);
        }
#pragma unroll
        for (int nt = 0; nt < 4; ++nt) {
            bfr[nt][0] = ld8(&Bs[wc + nt * 16 + nl][kg]);
            bfr[nt][1] = ld8(&Bs[wc + nt * 16 + nl][kg + 32]);
        }
#pragma unroll
        for (int mt = 0; mt < 2; ++mt)
#pragma unroll
            for (int nt = 0; nt < 4; ++nt) {
                acc[mt][nt] = __builtin_amdgcn_mfma_f32_16x16x32_bf16(af[mt][0], bfr[nt][0], acc[mt][nt], 0, 0, 0);
                acc[mt][nt] = __builtin_amdgcn_mfma_f32_16x16x32_bf16(af[mt][1], bfr[nt][1], acc[mt][nt], 0, 0, 0);
            }
    }

    const int prow = (lane >> 4) * 4;
#pragma unroll
    for (int mt = 0; mt < 2; ++mt)
#pragma unroll
        for (int r = 0; r < 4; ++r) {
            const int n = n0 + wr + mt * 16 + prow + r;
#pragma unroll
            for (int nt = 0; nt < 4; ++nt) {
                const int e = e0 + wc + nt * 16 + nl;
                out[(size_t)n * 512 + e] = acc[mt][nt][r] + bo[e];
            }
        }
}

// ---------------------------------------------------------------------------
extern "C" void kernel_launch(void* const* d_in, const int* in_sizes, int n_in,
                              void* d_out, int out_size, void* d_ws, size_t ws_size,
                              hipStream_t stream)
{
    const float* q_in  = (const float*)d_in[0];
    const float* k_in  = (const float*)d_in[1];
    const float* v_in  = (const float*)d_in[2];
    // d_in[3] = mask (int32) — semantic no-op in the reference
    const float* Wq_in = (const float*)d_in[4];
    const float* bq_in = (const float*)d_in[5];
    const float* Wk_in = (const float*)d_in[6];
    const float* bk_in = (const float*)d_in[7];
    const float* Wv_in = (const float*)d_in[8];
    const float* bv_in = (const float*)d_in[9];
    const float* wvq   = (const float*)d_in[10];
    const float* wvk   = (const float*)d_in[11];
    const float* wvv   = (const float*)d_in[12];
    const float* Wq    = (const float*)d_in[13];
    const float* bq    = (const float*)d_in[14];
    const float* Wk    = (const float*)d_in[15];
    const float* bk    = (const float*)d_in[16];
    const float* Wv    = (const float*)d_in[17];
    const float* bv    = (const float*)d_in[18];
    const float* Wo    = (const float*)d_in[19];
    const float* bo    = (const float*)d_in[20];

    u16* ws = (u16*)d_ws;
    u16* Qb = ws;                          // (B,H,S,D) bf16, 4M elems
    u16* Kb = ws + (size_t)(1 << 22);
    u16* Vb = ws + (size_t)(2 << 22);
    u16* Ob = ws + (size_t)3 * (1 << 22);  // (B,S,E) bf16
    u16* Wb = ws + (size_t)4 * (1 << 22);  // Wo bf16, 512K elems

    proj_kernel<<<PROJ_ROW_BLOCKS + 256, 256, 0, stream>>>(q_in, k_in, v_in,
        Wq_in, bq_in, Wk_in, bk_in, Wv_in, bv_in,
        wvq, wvk, wvv, Wq, bq, Wk, bk, Wv, bv,
        Wo, Wb, Qb, Kb, Vb);
    attn_kernel<<<1024, 256, 0, stream>>>(Qb, Kb, Vb, Ob);
    out_kernel<<<512, 256, 0, stream>>>(Qb, Ob, Wb, bo, (float*)d_out);
}